// Round 10
// baseline (249.563 us; speedup 1.0000x reference)
//
#include <hip/hip_runtime.h>

typedef __attribute__((ext_vector_type(8))) _Float16 half8;
typedef __attribute__((ext_vector_type(4))) _Float16 half4v;
typedef __attribute__((ext_vector_type(4))) float floatx4;

#define NB 128
#define NN 64
#define NV 14
#define PP 32
#define SS 14
#define HH 128
#define DE 64
#define NCLS 5
#define PITCH 136   // halves; 272 B rows -> max 2-way bank aliasing (free)

// fragment-major weight offsets (halves). layout: [nt][ks][lane][8]
#define OFF_W2   0
#define OFF_W3   16384
#define OFF_W2PV 24576
#define OFF_W3PV 40960
#define OFF_FO1  49152
#define OFF_FO2  69632
#define OFF_FO3  86016

__device__ __forceinline__ floatx4 MFMA(half8 a, half8 b, floatx4 c) {
  return __builtin_amdgcn_mfma_f32_16x16x32_f16(a, b, c, 0, 0, 0);
}

// relu(acc+bias) -> 4 fp16 packed in 2 u32
__device__ __forceinline__ uint2 pack4(floatx4 a, float4 bb) {
  half4v h;
  h[0] = (_Float16)fmaxf(a[0] + bb.x, 0.f);
  h[1] = (_Float16)fmaxf(a[1] + bb.y, 0.f);
  h[2] = (_Float16)fmaxf(a[2] + bb.z, 0.f);
  h[3] = (_Float16)fmaxf(a[3] + bb.w, 0.f);
  union { half4v h4; uint2 u; } cv; cv.h4 = h;
  return cv.u;
}

// ---------------- K0: fp16 layer-1 terms (+bias fold), frag-major weights, d_out zero ----------------
__global__ __launch_bounds__(256) void k0_prep(
    const float* __restrict__ x, const float* __restrict__ y,
    const float* __restrict__ fr1_w, const float* __restrict__ fr1_b,
    const float* __restrict__ fr1pv_w, const float* __restrict__ fr1pv_b,
    const float* __restrict__ fr2_w, const float* __restrict__ fr3_w,
    const float* __restrict__ fr2pv_w, const float* __restrict__ fr3pv_w,
    const float* __restrict__ fo1_w, const float* __restrict__ fo2_w,
    const float* __restrict__ fo3_w,
    _Float16* __restrict__ A1h, _Float16* __restrict__ B1h,
    _Float16* __restrict__ A1pvh, _Float16* __restrict__ B1pvh,
    _Float16* __restrict__ WT, float* __restrict__ dout) {
  int blk = blockIdx.x;
  int tid = threadIdx.x;
  if (blk < 768) {
    int mat = blk >> 8, sub = blk & 255;
    int b = sub >> 1, n0 = (sub & 1) << 5;
    __shared__ float sxT[32 * 33];
    for (int i = tid; i < 32 * PP; i += 256) {
      int p = i >> 5, n = i & 31;
      sxT[n * 33 + p] = x[b * (PP * NN) + p * 64 + n0 + n];
    }
    __syncthreads();
    const float* w; _Float16* outp; const float* bias;
    if (mat == 0)      { w = fr1_w;           outp = A1h;   bias = fr1_b; }
    else if (mat == 1) { w = fr1_w + 32 * HH; outp = B1h;   bias = nullptr; }
    else               { w = fr1pv_w;         outp = A1pvh; bias = fr1pv_b; }
    for (int o = tid; o < 32 * 32; o += 256) {
      int n = o >> 5, jc = o & 31;
      float4 acc = {0.f, 0.f, 0.f, 0.f};
      const float* xr = &sxT[n * 33];
#pragma unroll 8
      for (int k = 0; k < PP; k++) {
        float xv = xr[k];
        float4 wv = ((const float4*)w)[k * 32 + jc];
        acc.x += xv * wv.x; acc.y += xv * wv.y;
        acc.z += xv * wv.z; acc.w += xv * wv.w;
      }
      if (bias) {
        float4 bv = ((const float4*)bias)[jc];
        acc.x += bv.x; acc.y += bv.y; acc.z += bv.z; acc.w += bv.w;
      }
      half4v hv;
      hv[0] = (_Float16)acc.x; hv[1] = (_Float16)acc.y;
      hv[2] = (_Float16)acc.z; hv[3] = (_Float16)acc.w;
      *(half4v*)(&outp[(b * NN + n0 + n) * HH + jc * 4]) = hv;
    }
  } else if (blk < 896) {
    int b = blk - 768;
    __shared__ float syT[NV * 15];
    for (int i = tid; i < SS * NV; i += 256) {
      int s = i / NV, v = i - s * NV;
      syT[v * 15 + s] = y[b * (SS * NV) + i];
    }
    __syncthreads();
    const float4* w4 = (const float4*)(fr1pv_w + 32 * HH);
    for (int o = tid; o < NV * 32; o += 256) {
      int v = o >> 5, jc = o & 31;
      float4 acc = {0.f, 0.f, 0.f, 0.f};
#pragma unroll
      for (int s = 0; s < SS; s++) {
        float yv = syT[v * 15 + s];
        float4 wv = w4[s * 32 + jc];
        acc.x += yv * wv.x; acc.y += yv * wv.y;
        acc.z += yv * wv.z; acc.w += yv * wv.w;
      }
      half4v hv;
      hv[0] = (_Float16)acc.x; hv[1] = (_Float16)acc.y;
      hv[2] = (_Float16)acc.z; hv[3] = (_Float16)acc.w;
      *(half4v*)(&B1pvh[(b * NV + v) * HH + jc * 4]) = hv;
    }
  } else if (blk < 952) {
    // frag-major transform, 8 slices per matrix:
    // dst[((nt*NKS+ks)*64 + lane)*8 + j] = src[(ks*32+q*8+j)*N + nt*16+c]
    int t = blk - 896;
    int wid = t >> 3, slice = t & 7;
    const float* src; int N, NKS, NTN; _Float16* dst;
    switch (wid) {
      case 0: src = fr2_w;   N = 128; NKS = 4; NTN = 8; dst = WT + OFF_W2;   break;
      case 1: src = fr3_w;   N = 64;  NKS = 4; NTN = 4; dst = WT + OFF_W3;   break;
      case 2: src = fr2pv_w; N = 128; NKS = 4; NTN = 8; dst = WT + OFF_W2PV; break;
      case 3: src = fr3pv_w; N = 64;  NKS = 4; NTN = 4; dst = WT + OFF_W3PV; break;
      case 4: src = fo1_w;   N = 128; NKS = 5; NTN = 8; dst = WT + OFF_FO1;  break;
      case 5: src = fo2_w;   N = 128; NKS = 4; NTN = 8; dst = WT + OFF_FO2;  break;
      default: src = fo3_w;  N = 64;  NKS = 4; NTN = 4; dst = WT + OFF_FO3;  break;
    }
    int tot = NTN * NKS * 512;
    int sz = tot >> 3;
    int hi = (slice + 1) * sz;
    for (int i = slice * sz + tid; i < hi; i += 256) {
      int j = i & 7, l = (i >> 3) & 63, f = i >> 9;
      int ks = f % NKS, nt = f / NKS;
      int cc = l & 15, qq = l >> 4;
      dst[i] = (_Float16)src[(ks * 32 + qq * 8 + j) * N + nt * 16 + cc];
    }
  } else {
    for (int i = tid; i < NB * NCLS; i += 256) dout[i] = 0.f;
  }
}

// ---------------- EDGE_PP: cooperative h1 build + register weights ----------------
// block = (b, 4 receivers) = 252 rows, 4 chunks x 64. Per chunk:
//   A: wave builds ITS 16 rows of h1 -> sH      (no redundancy)
//   B: wave computes its 2 nt tiles for all rows; h2 packed in regs
//   C: publish h2 to sH (in place, after WAR barrier)
//   D: layer3 (1 nt tile / wave) -> segmented reduce into sEb
__global__ __launch_bounds__(256) void edge_pp(
    const _Float16* __restrict__ A1h, const _Float16* __restrict__ B1h,
    const float* __restrict__ fr2_b, const float* __restrict__ fr3_b,
    const _Float16* __restrict__ WT, float* __restrict__ Epp) {
  __shared__ _Float16 sB1[64 * PITCH];   // 17408 B
  __shared__ _Float16 sA1[4 * PITCH];    // 1088 B
  __shared__ _Float16 sH[64 * PITCH];    // 17408 B  (h1, then h2 in place)
  __shared__ float sEb[4 * 64];          // 1024 B   total ~36.9 KB -> 4 blocks/CU
  int tid = threadIdx.x;
  int b = blockIdx.x >> 4, r0 = (blockIdx.x & 15) << 2;
  sEb[tid] = 0.f;
  for (int i = tid; i < 1024; i += 256) {
    int row = i >> 4, cc = i & 15;
    *(uint4*)(&sB1[row * PITCH + cc * 8]) = *(const uint4*)(&B1h[(b * NN + row) * HH + cc * 8]);
  }
  if (tid < 64) {
    int row = tid >> 4, cc = tid & 15;
    *(uint4*)(&sA1[row * PITCH + cc * 8]) = *(const uint4*)(&A1h[(b * NN + r0 + row) * HH + cc * 8]);
  }
  int lane = tid & 63, wv = tid >> 6;
  int c = lane & 15, q = lane >> 4;
  // persistent register weights: W2 frags for nts {2wv, 2wv+1}
  half8 w2f[2][4];
#pragma unroll
  for (int nt2 = 0; nt2 < 2; nt2++)
#pragma unroll
    for (int ks = 0; ks < 4; ks++)
      w2f[nt2][ks] = *(const half8*)(&WT[OFF_W2 + (((wv * 2 + nt2) * 4 + ks) << 9) + (lane << 3)]);
  float4 bb2[2];
  bb2[0] = *(const float4*)(&fr2_b[(wv * 2) * 16 + q * 4]);
  bb2[1] = *(const float4*)(&fr2_b[(wv * 2 + 1) * 16 + q * 4]);
  float bb3 = fr3_b[wv * 16 + c];
  __syncthreads();
#pragma unroll 1
  for (int ch = 0; ch < 4; ch++) {
    int base = ch * 64;
    // ---- A: build own 16 rows of h1 ----
    {
      int rl = base + wv * 16 + c;
      int rr = rl / 63; if (rr > 3) rr = 3;
      int jj = rl - rr * 63; if (jj > 62) jj = 62;
      int s = jj + (jj >= r0 + rr ? 1 : 0);
#pragma unroll
      for (int ks = 0; ks < 4; ks++) {
        half8 av = *(const half8*)(&sA1[rr * PITCH + ks * 32 + q * 8]);
        half8 bv = *(const half8*)(&sB1[s * PITCH + ks * 32 + q * 8]);
        half8 h = av + bv;
#pragma unroll
        for (int j = 0; j < 8; j++) h[j] = h[j] > (_Float16)0.f ? h[j] : (_Float16)0.f;
        *(half8*)(&sH[(wv * 16 + c) * PITCH + ks * 32 + q * 8]) = h;
      }
    }
    __syncthreads();
    // ---- B: layer2, own 2 nt tiles for all 64 rows; h2 in regs ----
    uint2 h2p[4][2];
#pragma unroll
    for (int rt = 0; rt < 4; rt++) {
      half8 hfr[4];
#pragma unroll
      for (int ks = 0; ks < 4; ks++)
        hfr[ks] = *(const half8*)(&sH[(rt * 16 + c) * PITCH + ks * 32 + q * 8]);
#pragma unroll
      for (int nt2 = 0; nt2 < 2; nt2++) {
        floatx4 acc = {0.f, 0.f, 0.f, 0.f};
#pragma unroll
        for (int ks = 0; ks < 4; ks++) acc = MFMA(w2f[nt2][ks], hfr[ks], acc);
        h2p[rt][nt2] = pack4(acc, bb2[nt2]);
      }
    }
    __syncthreads();
    // ---- C: publish h2 (rows rt*16+c, cols wv*32..+31) ----
#pragma unroll
    for (int rt = 0; rt < 4; rt++)
#pragma unroll
      for (int nt2 = 0; nt2 < 2; nt2++) {
        union { uint2 u; half4v h; } cv; cv.u = h2p[rt][nt2];
        *(half4v*)(&sH[(rt * 16 + c) * PITCH + (wv * 2 + nt2) * 16 + q * 4]) = cv.h;
      }
    __syncthreads();
    // ---- D: layer3, own 16 cols; segmented reduce ----
    half8 w3f[4];
#pragma unroll
    for (int ks = 0; ks < 4; ks++)
      w3f[ks] = *(const half8*)(&WT[OFF_W3 + ((wv * 4 + ks) << 9) + (lane << 3)]);
    int col = wv * 16 + c;
#pragma unroll
    for (int rt = 0; rt < 4; rt++) {
      half8 a2[4];
#pragma unroll
      for (int ks = 0; ks < 4; ks++)
        a2[ks] = *(const half8*)(&sH[(rt * 16 + c) * PITCH + ks * 32 + q * 8]);
      floatx4 e = {0.f, 0.f, 0.f, 0.f};
#pragma unroll
      for (int ks = 0; ks < 4; ks++) e = MFMA(a2[ks], w3f[ks], e);
      float v0 = fmaxf(e[0] + bb3, 0.f);
      float v1 = fmaxf(e[1] + bb3, 0.f);
      float v2 = fmaxf(e[2] + bb3, 0.f);
      float v3 = fmaxf(e[3] + bb3, 0.f);
      int tstart = base + rt * 16;
      if (tstart / 63 == (tstart + 15) / 63 && tstart + 15 < 252) {
        // whole tile in one receiver segment: cross-q reduce, 1 atomic / col
        float s2 = v0 + v1 + v2 + v3;
        s2 += __shfl_xor(s2, 16);
        s2 += __shfl_xor(s2, 32);
        if (q == 0) atomicAdd(&sEb[(tstart / 63) * 64 + col], s2);
      } else {
        int rbase = tstart + q * 4;
        float vs[4] = {v0, v1, v2, v3};
#pragma unroll
        for (int rg = 0; rg < 4; rg++) {
          int r2 = rbase + rg;
          if (r2 < 252) atomicAdd(&sEb[(r2 / 63) * 64 + col], vs[rg]);
        }
      }
    }
    __syncthreads();
  }
  Epp[(b * NN + r0 + (tid >> 6)) * DE + (tid & 63)] = sEb[tid];
}

// ---------------- EDGE_PV: same cooperative structure; (b, 8 k-nodes) = 112 rows, 2 chunks ----------------
__global__ __launch_bounds__(256) void edge_pv(
    const _Float16* __restrict__ A1pvh, const _Float16* __restrict__ B1pvh,
    const float* __restrict__ fr2pv_b, const float* __restrict__ fr3pv_b,
    const _Float16* __restrict__ WT, float* __restrict__ Epv) {
  __shared__ _Float16 sApv[8 * PITCH];    // 2176 B
  __shared__ _Float16 sBpv[14 * PITCH];   // 3808 B
  __shared__ _Float16 sH[64 * PITCH];     // 17408 B
  __shared__ float sEb[8 * 64];           // 2048 B   total ~25.4 KB -> 6 blocks/CU
  int tid = threadIdx.x;
  int b = blockIdx.x >> 3, k0g = (blockIdx.x & 7) << 3;
  for (int i = tid; i < 512; i += 256) sEb[i] = 0.f;
  if (tid < 128) {
    int row = tid >> 4, cc = tid & 15;
    *(uint4*)(&sApv[row * PITCH + cc * 8]) = *(const uint4*)(&A1pvh[(b * NN + k0g + row) * HH + cc * 8]);
  }
  for (int i = tid; i < 14 * 16; i += 256) {
    int row = i >> 4, cc = i & 15;
    *(uint4*)(&sBpv[row * PITCH + cc * 8]) = *(const uint4*)(&B1pvh[(b * NV + row) * HH + cc * 8]);
  }
  int lane = tid & 63, wv = tid >> 6;
  int c = lane & 15, q = lane >> 4;
  half8 w2f[2][4];
#pragma unroll
  for (int nt2 = 0; nt2 < 2; nt2++)
#pragma unroll
    for (int ks = 0; ks < 4; ks++)
      w2f[nt2][ks] = *(const half8*)(&WT[OFF_W2PV + (((wv * 2 + nt2) * 4 + ks) << 9) + (lane << 3)]);
  float4 bb2[2];
  bb2[0] = *(const float4*)(&fr2pv_b[(wv * 2) * 16 + q * 4]);
  bb2[1] = *(const float4*)(&fr2pv_b[(wv * 2 + 1) * 16 + q * 4]);
  float bb3 = fr3pv_b[wv * 16 + c];
  __syncthreads();
#pragma unroll 1
  for (int ch = 0; ch < 2; ch++) {
    int base = ch * 64;
    {
      int rl = base + wv * 16 + c;
      int rr = rl / 14; if (rr > 7) rr = 7;
      int v = rl - rr * 14; if (v > 13) v = 13;
#pragma unroll
      for (int ks = 0; ks < 4; ks++) {
        half8 av = *(const half8*)(&sApv[rr * PITCH + ks * 32 + q * 8]);
        half8 bv = *(const half8*)(&sBpv[v * PITCH + ks * 32 + q * 8]);
        half8 h = av + bv;
#pragma unroll
        for (int j = 0; j < 8; j++) h[j] = h[j] > (_Float16)0.f ? h[j] : (_Float16)0.f;
        *(half8*)(&sH[(wv * 16 + c) * PITCH + ks * 32 + q * 8]) = h;
      }
    }
    __syncthreads();
    uint2 h2p[4][2];
#pragma unroll
    for (int rt = 0; rt < 4; rt++) {
      half8 hfr[4];
#pragma unroll
      for (int ks = 0; ks < 4; ks++)
        hfr[ks] = *(const half8*)(&sH[(rt * 16 + c) * PITCH + ks * 32 + q * 8]);
#pragma unroll
      for (int nt2 = 0; nt2 < 2; nt2++) {
        floatx4 acc = {0.f, 0.f, 0.f, 0.f};
#pragma unroll
        for (int ks = 0; ks < 4; ks++) acc = MFMA(w2f[nt2][ks], hfr[ks], acc);
        h2p[rt][nt2] = pack4(acc, bb2[nt2]);
      }
    }
    __syncthreads();
#pragma unroll
    for (int rt = 0; rt < 4; rt++)
#pragma unroll
      for (int nt2 = 0; nt2 < 2; nt2++) {
        union { uint2 u; half4v h; } cv; cv.u = h2p[rt][nt2];
        *(half4v*)(&sH[(rt * 16 + c) * PITCH + (wv * 2 + nt2) * 16 + q * 4]) = cv.h;
      }
    __syncthreads();
    half8 w3f[4];
#pragma unroll
    for (int ks = 0; ks < 4; ks++)
      w3f[ks] = *(const half8*)(&WT[OFF_W3PV + ((wv * 4 + ks) << 9) + (lane << 3)]);
    int col = wv * 16 + c;
#pragma unroll
    for (int rt = 0; rt < 4; rt++) {
      half8 a2[4];
#pragma unroll
      for (int ks = 0; ks < 4; ks++)
        a2[ks] = *(const half8*)(&sH[(rt * 16 + c) * PITCH + ks * 32 + q * 8]);
      floatx4 e = {0.f, 0.f, 0.f, 0.f};
#pragma unroll
      for (int ks = 0; ks < 4; ks++) e = MFMA(a2[ks], w3f[ks], e);
      int rbase = base + rt * 16 + q * 4;
      float vs[4];
      vs[0] = fmaxf(e[0] + bb3, 0.f);
      vs[1] = fmaxf(e[1] + bb3, 0.f);
      vs[2] = fmaxf(e[2] + bb3, 0.f);
      vs[3] = fmaxf(e[3] + bb3, 0.f);
#pragma unroll
      for (int rg = 0; rg < 4; rg++) {
        int r2 = rbase + rg;
        if (r2 < 112) atomicAdd(&sEb[(r2 / 14) * 64 + col], vs[rg]);
      }
    }
    __syncthreads();
  }
  for (int i = tid; i < 512; i += 256)
    Epv[(b * NN + k0g + (i >> 6)) * DE + (i & 63)] = sEb[i];
}

// ---------------- NODE: C=[x|Epp|Epv] -> fo1,fo2,fo3 -> pool -> fc; block=(b, 8 nodes) ----------------
__global__ __launch_bounds__(256) void node_out(
    const float* __restrict__ x, const float* __restrict__ Epp,
    const float* __restrict__ Epv,
    const float* __restrict__ fo1_b, const float* __restrict__ fo2_b,
    const float* __restrict__ fo3_b,
    const float* __restrict__ fc_w, const float* __restrict__ fc_b,
    const _Float16* __restrict__ WT, float* __restrict__ out) {
  __shared__ _Float16 sC[16 * 168];
  __shared__ _Float16 sHa[16 * PITCH];
  __shared__ _Float16 sHb[16 * PITCH];
  __shared__ float sPool[64];
  int tid = threadIdx.x;
  int b = blockIdx.x >> 3, r0 = (blockIdx.x & 7) << 3;
  for (int i = tid; i < 16 * 32; i += 256) {
    int row = i >> 5, p = i & 31;
    float v = (row < 8) ? x[b * (PP * NN) + p * 64 + r0 + row] : 0.f;
    sC[row * 168 + p] = (_Float16)v;
  }
  for (int i = tid; i < 16 * 64; i += 256) {
    int row = i >> 6, d = i & 63;
    float vpp = (row < 8) ? Epp[(b * NN + r0 + row) * DE + d] : 0.f;
    float vpv = (row < 8) ? Epv[(b * NN + r0 + row) * DE + d] : 0.f;
    sC[row * 168 + 32 + d] = (_Float16)vpp;
    sC[row * 168 + 96 + d] = (_Float16)vpv;
  }
  __syncthreads();
  int lane = tid & 63, wv = tid >> 6;
  int c = lane & 15, q = lane >> 4;
  half8 cf[5];
#pragma unroll
  for (int ks = 0; ks < 5; ks++)
    cf[ks] = *(const half8*)(&sC[c * 168 + ks * 32 + q * 8]);
#pragma unroll
  for (int nt2 = 0; nt2 < 2; nt2++) {
    int nt = wv * 2 + nt2;
    floatx4 a0 = {0.f, 0.f, 0.f, 0.f};
#pragma unroll
    for (int ks = 0; ks < 5; ks++) {
      half8 wf = *(const half8*)(&WT[OFF_FO1 + ((nt * 5 + ks) << 9) + (lane << 3)]);
      a0 = MFMA(wf, cf[ks], a0);
    }
    float4 bb = *(const float4*)(&fo1_b[nt * 16 + q * 4]);
    half4v h0;
    h0[0] = (_Float16)fmaxf(a0[0] + bb.x, 0.f);
    h0[1] = (_Float16)fmaxf(a0[1] + bb.y, 0.f);
    h0[2] = (_Float16)fmaxf(a0[2] + bb.z, 0.f);
    h0[3] = (_Float16)fmaxf(a0[3] + bb.w, 0.f);
    *(half4v*)(&sHa[c * PITCH + nt * 16 + q * 4]) = h0;
  }
  __syncthreads();
  half8 g1[4];
#pragma unroll
  for (int ks = 0; ks < 4; ks++)
    g1[ks] = *(const half8*)(&sHa[c * PITCH + ks * 32 + q * 8]);
#pragma unroll
  for (int nt2 = 0; nt2 < 2; nt2++) {
    int nt = wv * 2 + nt2;
    floatx4 a0 = {0.f, 0.f, 0.f, 0.f};
#pragma unroll
    for (int ks = 0; ks < 4; ks++) {
      half8 wf = *(const half8*)(&WT[OFF_FO2 + ((nt * 4 + ks) << 9) + (lane << 3)]);
      a0 = MFMA(wf, g1[ks], a0);
    }
    float4 bb = *(const float4*)(&fo2_b[nt * 16 + q * 4]);
    half4v h0;
    h0[0] = (_Float16)fmaxf(a0[0] + bb.x, 0.f);
    h0[1] = (_Float16)fmaxf(a0[1] + bb.y, 0.f);
    h0[2] = (_Float16)fmaxf(a0[2] + bb.z, 0.f);
    h0[3] = (_Float16)fmaxf(a0[3] + bb.w, 0.f);
    *(half4v*)(&sHb[c * PITCH + nt * 16 + q * 4]) = h0;
  }
  __syncthreads();
  half8 g2[4];
#pragma unroll
  for (int ks = 0; ks < 4; ks++)
    g2[ks] = *(const half8*)(&sHb[c * PITCH + ks * 32 + q * 8]);
  floatx4 e0 = {0.f, 0.f, 0.f, 0.f};
#pragma unroll
  for (int ks = 0; ks < 4; ks++) {
    half8 wf = *(const half8*)(&WT[OFF_FO3 + ((wv * 4 + ks) << 9) + (lane << 3)]);
    e0 = MFMA(g2[ks], wf, e0);
  }
  float bb3 = fo3_b[wv * 16 + c];
  float s = 0.f;
  if (q < 2) {
#pragma unroll
    for (int rg = 0; rg < 4; rg++) s += fmaxf(e0[rg] + bb3, 0.f);
  }
  s += __shfl_xor(s, 16);
  if (lane < 16) sPool[wv * 16 + c] = s;
  __syncthreads();
  if (tid < NCLS) {
    float o = ((blockIdx.x & 7) == 0) ? fc_b[tid] : 0.f;
#pragma unroll
    for (int d = 0; d < 64; d++) o += sPool[d] * fc_w[d * NCLS + tid];
    atomicAdd(&out[b * NCLS + tid], o);
  }
}

extern "C" void kernel_launch(void* const* d_in, const int* in_sizes, int n_in,
                              void* d_out, int out_size, void* d_ws, size_t ws_size,
                              hipStream_t stream) {
  const float* x = (const float*)d_in[0];
  const float* y = (const float*)d_in[1];
  const float* fr1_w = (const float*)d_in[2];  const float* fr1_b = (const float*)d_in[3];
  const float* fr2_w = (const float*)d_in[4];  const float* fr2_b = (const float*)d_in[5];
  const float* fr3_w = (const float*)d_in[6];  const float* fr3_b = (const float*)d_in[7];
  const float* fr1pv_w = (const float*)d_in[8];  const float* fr1pv_b = (const float*)d_in[9];
  const float* fr2pv_w = (const float*)d_in[10]; const float* fr2pv_b = (const float*)d_in[11];
  const float* fr3pv_w = (const float*)d_in[12]; const float* fr3pv_b = (const float*)d_in[13];
  const float* fo1_w = (const float*)d_in[14];  const float* fo1_b = (const float*)d_in[15];
  const float* fo2_w = (const float*)d_in[16];  const float* fo2_b = (const float*)d_in[17];
  const float* fo3_w = (const float*)d_in[18];  const float* fo3_b = (const float*)d_in[19];
  const float* fc_w = (const float*)d_in[20];   const float* fc_b = (const float*)d_in[21];

  char* ws = (char*)d_ws;
  _Float16* A1h   = (_Float16*)(ws);                 // [128][64][128] fp16 (bias folded)
  _Float16* B1h   = (_Float16*)(ws + (2u << 20));
  _Float16* A1pvh = (_Float16*)(ws + (4u << 20));    // (bias folded)
  _Float16* B1pvh = (_Float16*)(ws + (6u << 20));    // [128][14][128] fp16
  _Float16* WT    = (_Float16*)(ws + (7u << 20));    // frag-major fp16 weights (~200 KB)
  float* Epp      = (float*)(ws + (8u << 20));       // [128][64][64] f32
  float* Epv      = (float*)(ws + (10u << 20));      // [128][64][64] f32

  k0_prep<<<953, 256, 0, stream>>>(x, y, fr1_w, fr1_b, fr1pv_w, fr1pv_b,
                                   fr2_w, fr3_w, fr2pv_w, fr3pv_w,
                                   fo1_w, fo2_w, fo3_w,
                                   A1h, B1h, A1pvh, B1pvh, WT, (float*)d_out);
  edge_pp<<<NB * 16, 256, 0, stream>>>(A1h, B1h, fr2_b, fr3_b, WT, Epp);
  edge_pv<<<NB * 8, 256, 0, stream>>>(A1pvh, B1pvh, fr2pv_b, fr3pv_b, WT, Epv);
  node_out<<<NB * 8, 256, 0, stream>>>(x, Epp, Epv, fo1_b, fo2_b, fo3_b,
                                       fc_w, fc_b, WT, (float*)d_out);
}

// Round 11
// 246.453 us; speedup vs baseline: 1.0126x; 1.0126x over previous
//
#include <hip/hip_runtime.h>

typedef __attribute__((ext_vector_type(8))) _Float16 half8;
typedef __attribute__((ext_vector_type(4))) _Float16 half4v;
typedef __attribute__((ext_vector_type(4))) float floatx4;

#define NB 128
#define NN 64
#define NV 14
#define PP 32
#define SS 14
#define HH 128
#define DE 64
#define NCLS 5
#define PITCH 136   // halves; 272 B rows -> max 2-way bank aliasing (free)

// fragment-major weight offsets (halves). layout: [nt][ks][lane][8]
#define OFF_W2   0
#define OFF_W3   16384
#define OFF_W2PV 24576
#define OFF_W3PV 40960
#define OFF_FO1  49152
#define OFF_FO2  69632
#define OFF_FO3  86016

__device__ __forceinline__ floatx4 MFMA(half8 a, half8 b, floatx4 c) {
  return __builtin_amdgcn_mfma_f32_16x16x32_f16(a, b, c, 0, 0, 0);
}

// relu(acc+bias) -> 4 fp16 packed in 2 u32
__device__ __forceinline__ uint2 pack4(floatx4 a, float4 bb) {
  half4v h;
  h[0] = (_Float16)fmaxf(a[0] + bb.x, 0.f);
  h[1] = (_Float16)fmaxf(a[1] + bb.y, 0.f);
  h[2] = (_Float16)fmaxf(a[2] + bb.z, 0.f);
  h[3] = (_Float16)fmaxf(a[3] + bb.w, 0.f);
  union { half4v h4; uint2 u; } cv; cv.h4 = h;
  return cv.u;
}

// ---------------- K0: fp16 layer-1 terms (+bias fold), frag-major weights, d_out zero ----------------
__global__ __launch_bounds__(256) void k0_prep(
    const float* __restrict__ x, const float* __restrict__ y,
    const float* __restrict__ fr1_w, const float* __restrict__ fr1_b,
    const float* __restrict__ fr1pv_w, const float* __restrict__ fr1pv_b,
    const float* __restrict__ fr2_w, const float* __restrict__ fr3_w,
    const float* __restrict__ fr2pv_w, const float* __restrict__ fr3pv_w,
    const float* __restrict__ fo1_w, const float* __restrict__ fo2_w,
    const float* __restrict__ fo3_w,
    _Float16* __restrict__ A1h, _Float16* __restrict__ B1h,
    _Float16* __restrict__ A1pvh, _Float16* __restrict__ B1pvh,
    _Float16* __restrict__ WT, float* __restrict__ dout) {
  int blk = blockIdx.x;
  int tid = threadIdx.x;
  if (blk < 768) {
    int mat = blk >> 8, sub = blk & 255;
    int b = sub >> 1, n0 = (sub & 1) << 5;
    __shared__ float sxT[32 * 33];
    for (int i = tid; i < 32 * PP; i += 256) {
      int p = i >> 5, n = i & 31;
      sxT[n * 33 + p] = x[b * (PP * NN) + p * 64 + n0 + n];
    }
    __syncthreads();
    const float* w; _Float16* outp; const float* bias;
    if (mat == 0)      { w = fr1_w;           outp = A1h;   bias = fr1_b; }
    else if (mat == 1) { w = fr1_w + 32 * HH; outp = B1h;   bias = nullptr; }
    else               { w = fr1pv_w;         outp = A1pvh; bias = fr1pv_b; }
    for (int o = tid; o < 32 * 32; o += 256) {
      int n = o >> 5, jc = o & 31;
      float4 acc = {0.f, 0.f, 0.f, 0.f};
      const float* xr = &sxT[n * 33];
#pragma unroll 8
      for (int k = 0; k < PP; k++) {
        float xv = xr[k];
        float4 wv = ((const float4*)w)[k * 32 + jc];
        acc.x += xv * wv.x; acc.y += xv * wv.y;
        acc.z += xv * wv.z; acc.w += xv * wv.w;
      }
      if (bias) {
        float4 bv = ((const float4*)bias)[jc];
        acc.x += bv.x; acc.y += bv.y; acc.z += bv.z; acc.w += bv.w;
      }
      half4v hv;
      hv[0] = (_Float16)acc.x; hv[1] = (_Float16)acc.y;
      hv[2] = (_Float16)acc.z; hv[3] = (_Float16)acc.w;
      *(half4v*)(&outp[(b * NN + n0 + n) * HH + jc * 4]) = hv;
    }
  } else if (blk < 896) {
    int b = blk - 768;
    __shared__ float syT[NV * 15];
    for (int i = tid; i < SS * NV; i += 256) {
      int s = i / NV, v = i - s * NV;
      syT[v * 15 + s] = y[b * (SS * NV) + i];
    }
    __syncthreads();
    const float4* w4 = (const float4*)(fr1pv_w + 32 * HH);
    for (int o = tid; o < NV * 32; o += 256) {
      int v = o >> 5, jc = o & 31;
      float4 acc = {0.f, 0.f, 0.f, 0.f};
#pragma unroll
      for (int s = 0; s < SS; s++) {
        float yv = syT[v * 15 + s];
        float4 wv = w4[s * 32 + jc];
        acc.x += yv * wv.x; acc.y += yv * wv.y;
        acc.z += yv * wv.z; acc.w += yv * wv.w;
      }
      half4v hv;
      hv[0] = (_Float16)acc.x; hv[1] = (_Float16)acc.y;
      hv[2] = (_Float16)acc.z; hv[3] = (_Float16)acc.w;
      *(half4v*)(&B1pvh[(b * NV + v) * HH + jc * 4]) = hv;
    }
  } else if (blk < 952) {
    // frag-major transform, 8 slices per matrix:
    // dst[((nt*NKS+ks)*64 + lane)*8 + j] = src[(ks*32+q*8+j)*N + nt*16+c]
    int t = blk - 896;
    int wid = t >> 3, slice = t & 7;
    const float* src; int N, NKS, NTN; _Float16* dst;
    switch (wid) {
      case 0: src = fr2_w;   N = 128; NKS = 4; NTN = 8; dst = WT + OFF_W2;   break;
      case 1: src = fr3_w;   N = 64;  NKS = 4; NTN = 4; dst = WT + OFF_W3;   break;
      case 2: src = fr2pv_w; N = 128; NKS = 4; NTN = 8; dst = WT + OFF_W2PV; break;
      case 3: src = fr3pv_w; N = 64;  NKS = 4; NTN = 4; dst = WT + OFF_W3PV; break;
      case 4: src = fo1_w;   N = 128; NKS = 5; NTN = 8; dst = WT + OFF_FO1;  break;
      case 5: src = fo2_w;   N = 128; NKS = 4; NTN = 8; dst = WT + OFF_FO2;  break;
      default: src = fo3_w;  N = 64;  NKS = 4; NTN = 4; dst = WT + OFF_FO3;  break;
    }
    int tot = NTN * NKS * 512;
    int sz = tot >> 3;
    int hi = (slice + 1) * sz;
    for (int i = slice * sz + tid; i < hi; i += 256) {
      int j = i & 7, l = (i >> 3) & 63, f = i >> 9;
      int ks = f % NKS, nt = f / NKS;
      int cc = l & 15, qq = l >> 4;
      dst[i] = (_Float16)src[(ks * 32 + qq * 8 + j) * N + nt * 16 + cc];
    }
  } else {
    for (int i = tid; i < NB * NCLS; i += 256) dout[i] = 0.f;
  }
}

// ---------------- EDGES: merged grid. blocks [0,2048) = pp, [2048,3072) = pv ----------------
// pp block = (b, 4 receivers) = 252 rows, 4 chunks x 64, r10 4-phase structure.
// pv block = (b, 8 k-nodes) = 112 rows, 2 chunks. Both share one 36928-B LDS carve.
__global__ __launch_bounds__(256) void edges(
    const _Float16* __restrict__ A1h, const _Float16* __restrict__ B1h,
    const _Float16* __restrict__ A1pvh, const _Float16* __restrict__ B1pvh,
    const float* __restrict__ fr2_b, const float* __restrict__ fr3_b,
    const float* __restrict__ fr2pv_b, const float* __restrict__ fr3pv_b,
    const _Float16* __restrict__ WT,
    float* __restrict__ Epp, float* __restrict__ Epv) {
  __shared__ uint4 smem4[2308];          // 36928 B
  _Float16* sm = (_Float16*)smem4;
  int tid = threadIdx.x;
  int lane = tid & 63, wv = tid >> 6;
  int c = lane & 15, q = lane >> 4;
  if (blockIdx.x < 2048) {
    // ======================= PP branch =======================
    _Float16* sB1 = sm;                  // 64 x PITCH
    _Float16* sA1 = sm + 64 * PITCH;     // 4 x PITCH
    _Float16* sH  = sm + 68 * PITCH;     // 64 x PITCH (h1 then h2 in place)
    float* sEb    = (float*)(sm + 132 * PITCH);  // 4 x 64
    int b = blockIdx.x >> 4, r0 = (blockIdx.x & 15) << 2;
    sEb[tid] = 0.f;
    for (int i = tid; i < 1024; i += 256) {
      int row = i >> 4, cc = i & 15;
      *(uint4*)(&sB1[row * PITCH + cc * 8]) = *(const uint4*)(&B1h[(b * NN + row) * HH + cc * 8]);
    }
    if (tid < 64) {
      int row = tid >> 4, cc = tid & 15;
      *(uint4*)(&sA1[row * PITCH + cc * 8]) = *(const uint4*)(&A1h[(b * NN + r0 + row) * HH + cc * 8]);
    }
    // persistent register weights
    half8 w2f[2][4], w3f[4];
#pragma unroll
    for (int nt2 = 0; nt2 < 2; nt2++)
#pragma unroll
      for (int ks = 0; ks < 4; ks++)
        w2f[nt2][ks] = *(const half8*)(&WT[OFF_W2 + (((wv * 2 + nt2) * 4 + ks) << 9) + (lane << 3)]);
#pragma unroll
    for (int ks = 0; ks < 4; ks++)
      w3f[ks] = *(const half8*)(&WT[OFF_W3 + ((wv * 4 + ks) << 9) + (lane << 3)]);
    float4 bb2[2];
    bb2[0] = *(const float4*)(&fr2_b[(wv * 2) * 16 + q * 4]);
    bb2[1] = *(const float4*)(&fr2_b[(wv * 2 + 1) * 16 + q * 4]);
    float bb3 = fr3_b[wv * 16 + c];
    __syncthreads();
#pragma unroll 1
    for (int ch = 0; ch < 4; ch++) {
      int base = ch * 64;
      // A: build own 16 rows of h1
      {
        int rl = base + wv * 16 + c;
        int rr = rl / 63; if (rr > 3) rr = 3;
        int jj = rl - rr * 63; if (jj > 62) jj = 62;
        int s = jj + (jj >= r0 + rr ? 1 : 0);
#pragma unroll
        for (int ks = 0; ks < 4; ks++) {
          half8 av = *(const half8*)(&sA1[rr * PITCH + ks * 32 + q * 8]);
          half8 bv = *(const half8*)(&sB1[s * PITCH + ks * 32 + q * 8]);
          half8 h = av + bv;
#pragma unroll
          for (int j = 0; j < 8; j++) h[j] = h[j] > (_Float16)0.f ? h[j] : (_Float16)0.f;
          *(half8*)(&sH[(wv * 16 + c) * PITCH + ks * 32 + q * 8]) = h;
        }
      }
      __syncthreads();
      // B: layer2, own 2 nt tiles for all 64 rows; h2 packed in regs
      uint2 h2p[4][2];
#pragma unroll
      for (int rt = 0; rt < 4; rt++) {
        half8 hfr[4];
#pragma unroll
        for (int ks = 0; ks < 4; ks++)
          hfr[ks] = *(const half8*)(&sH[(rt * 16 + c) * PITCH + ks * 32 + q * 8]);
#pragma unroll
        for (int nt2 = 0; nt2 < 2; nt2++) {
          floatx4 acc = {0.f, 0.f, 0.f, 0.f};
#pragma unroll
          for (int ks = 0; ks < 4; ks++) acc = MFMA(w2f[nt2][ks], hfr[ks], acc);
          h2p[rt][nt2] = pack4(acc, bb2[nt2]);
        }
      }
      __syncthreads();
      // C: publish h2
#pragma unroll
      for (int rt = 0; rt < 4; rt++)
#pragma unroll
        for (int nt2 = 0; nt2 < 2; nt2++) {
          union { uint2 u; half4v h; } cv; cv.u = h2p[rt][nt2];
          *(half4v*)(&sH[(rt * 16 + c) * PITCH + (wv * 2 + nt2) * 16 + q * 4]) = cv.h;
        }
      __syncthreads();
      // D: layer3, own 16 cols; segmented reduce
      int col = wv * 16 + c;
#pragma unroll
      for (int rt = 0; rt < 4; rt++) {
        half8 a2[4];
#pragma unroll
        for (int ks = 0; ks < 4; ks++)
          a2[ks] = *(const half8*)(&sH[(rt * 16 + c) * PITCH + ks * 32 + q * 8]);
        floatx4 e = {0.f, 0.f, 0.f, 0.f};
#pragma unroll
        for (int ks = 0; ks < 4; ks++) e = MFMA(a2[ks], w3f[ks], e);
        float v0 = fmaxf(e[0] + bb3, 0.f);
        float v1 = fmaxf(e[1] + bb3, 0.f);
        float v2 = fmaxf(e[2] + bb3, 0.f);
        float v3 = fmaxf(e[3] + bb3, 0.f);
        int tstart = base + rt * 16;
        if (tstart / 63 == (tstart + 15) / 63 && tstart + 15 < 252) {
          float s2 = v0 + v1 + v2 + v3;
          s2 += __shfl_xor(s2, 16);
          s2 += __shfl_xor(s2, 32);
          if (q == 0) atomicAdd(&sEb[(tstart / 63) * 64 + col], s2);
        } else {
          int rbase = tstart + q * 4;
          float vs[4] = {v0, v1, v2, v3};
#pragma unroll
          for (int rg = 0; rg < 4; rg++) {
            int r2 = rbase + rg;
            if (r2 < 252) atomicAdd(&sEb[(r2 / 63) * 64 + col], vs[rg]);
          }
        }
      }
      __syncthreads();
    }
    Epp[(b * NN + r0 + (tid >> 6)) * DE + (tid & 63)] = sEb[tid];
  } else {
    // ======================= PV branch =======================
    _Float16* sApv = sm;                 // 8 x PITCH
    _Float16* sBpv = sm + 8 * PITCH;     // 14 x PITCH
    _Float16* sH   = sm + 22 * PITCH;    // 64 x PITCH
    float* sEb     = (float*)(sm + 86 * PITCH);  // 8 x 64
    int bx = blockIdx.x - 2048;
    int b = bx >> 3, k0g = (bx & 7) << 3;
    for (int i = tid; i < 512; i += 256) sEb[i] = 0.f;
    if (tid < 128) {
      int row = tid >> 4, cc = tid & 15;
      *(uint4*)(&sApv[row * PITCH + cc * 8]) = *(const uint4*)(&A1pvh[(b * NN + k0g + row) * HH + cc * 8]);
    }
    for (int i = tid; i < 14 * 16; i += 256) {
      int row = i >> 4, cc = i & 15;
      *(uint4*)(&sBpv[row * PITCH + cc * 8]) = *(const uint4*)(&B1pvh[(b * NV + row) * HH + cc * 8]);
    }
    half8 w2f[2][4], w3f[4];
#pragma unroll
    for (int nt2 = 0; nt2 < 2; nt2++)
#pragma unroll
      for (int ks = 0; ks < 4; ks++)
        w2f[nt2][ks] = *(const half8*)(&WT[OFF_W2PV + (((wv * 2 + nt2) * 4 + ks) << 9) + (lane << 3)]);
#pragma unroll
    for (int ks = 0; ks < 4; ks++)
      w3f[ks] = *(const half8*)(&WT[OFF_W3PV + ((wv * 4 + ks) << 9) + (lane << 3)]);
    float4 bb2[2];
    bb2[0] = *(const float4*)(&fr2pv_b[(wv * 2) * 16 + q * 4]);
    bb2[1] = *(const float4*)(&fr2pv_b[(wv * 2 + 1) * 16 + q * 4]);
    float bb3 = fr3pv_b[wv * 16 + c];
    __syncthreads();
#pragma unroll 1
    for (int ch = 0; ch < 2; ch++) {
      int base = ch * 64;
      {
        int rl = base + wv * 16 + c;
        int rr = rl / 14; if (rr > 7) rr = 7;
        int v = rl - rr * 14; if (v > 13) v = 13;
#pragma unroll
        for (int ks = 0; ks < 4; ks++) {
          half8 av = *(const half8*)(&sApv[rr * PITCH + ks * 32 + q * 8]);
          half8 bv = *(const half8*)(&sBpv[v * PITCH + ks * 32 + q * 8]);
          half8 h = av + bv;
#pragma unroll
          for (int j = 0; j < 8; j++) h[j] = h[j] > (_Float16)0.f ? h[j] : (_Float16)0.f;
          *(half8*)(&sH[(wv * 16 + c) * PITCH + ks * 32 + q * 8]) = h;
        }
      }
      __syncthreads();
      uint2 h2p[4][2];
#pragma unroll
      for (int rt = 0; rt < 4; rt++) {
        half8 hfr[4];
#pragma unroll
        for (int ks = 0; ks < 4; ks++)
          hfr[ks] = *(const half8*)(&sH[(rt * 16 + c) * PITCH + ks * 32 + q * 8]);
#pragma unroll
        for (int nt2 = 0; nt2 < 2; nt2++) {
          floatx4 acc = {0.f, 0.f, 0.f, 0.f};
#pragma unroll
          for (int ks = 0; ks < 4; ks++) acc = MFMA(w2f[nt2][ks], hfr[ks], acc);
          h2p[rt][nt2] = pack4(acc, bb2[nt2]);
        }
      }
      __syncthreads();
#pragma unroll
      for (int rt = 0; rt < 4; rt++)
#pragma unroll
        for (int nt2 = 0; nt2 < 2; nt2++) {
          union { uint2 u; half4v h; } cv; cv.u = h2p[rt][nt2];
          *(half4v*)(&sH[(rt * 16 + c) * PITCH + (wv * 2 + nt2) * 16 + q * 4]) = cv.h;
        }
      __syncthreads();
      int col = wv * 16 + c;
#pragma unroll
      for (int rt = 0; rt < 4; rt++) {
        half8 a2[4];
#pragma unroll
        for (int ks = 0; ks < 4; ks++)
          a2[ks] = *(const half8*)(&sH[(rt * 16 + c) * PITCH + ks * 32 + q * 8]);
        floatx4 e = {0.f, 0.f, 0.f, 0.f};
#pragma unroll
        for (int ks = 0; ks < 4; ks++) e = MFMA(a2[ks], w3f[ks], e);
        int rbase = base + rt * 16 + q * 4;
        float vs[4];
        vs[0] = fmaxf(e[0] + bb3, 0.f);
        vs[1] = fmaxf(e[1] + bb3, 0.f);
        vs[2] = fmaxf(e[2] + bb3, 0.f);
        vs[3] = fmaxf(e[3] + bb3, 0.f);
#pragma unroll
        for (int rg = 0; rg < 4; rg++) {
          int r2 = rbase + rg;
          if (r2 < 112) atomicAdd(&sEb[(r2 / 14) * 64 + col], vs[rg]);
        }
      }
      __syncthreads();
    }
    for (int i = tid; i < 512; i += 256)
      Epv[(b * NN + k0g + (i >> 6)) * DE + (i & 63)] = sEb[i];
  }
}

// ---------------- NODE: C=[x|Epp|Epv] -> fo1,fo2,fo3 -> pool -> fc; block=(b, 8 nodes) ----------------
__global__ __launch_bounds__(256) void node_out(
    const float* __restrict__ x, const float* __restrict__ Epp,
    const float* __restrict__ Epv,
    const float* __restrict__ fo1_b, const float* __restrict__ fo2_b,
    const float* __restrict__ fo3_b,
    const float* __restrict__ fc_w, const float* __restrict__ fc_b,
    const _Float16* __restrict__ WT, float* __restrict__ out) {
  __shared__ _Float16 sC[16 * 168];
  __shared__ _Float16 sHa[16 * PITCH];
  __shared__ _Float16 sHb[16 * PITCH];
  __shared__ float sPool[64];
  int tid = threadIdx.x;
  int b = blockIdx.x >> 3, r0 = (blockIdx.x & 7) << 3;
  for (int i = tid; i < 16 * 32; i += 256) {
    int row = i >> 5, p = i & 31;
    float v = (row < 8) ? x[b * (PP * NN) + p * 64 + r0 + row] : 0.f;
    sC[row * 168 + p] = (_Float16)v;
  }
  for (int i = tid; i < 16 * 64; i += 256) {
    int row = i >> 6, d = i & 63;
    float vpp = (row < 8) ? Epp[(b * NN + r0 + row) * DE + d] : 0.f;
    float vpv = (row < 8) ? Epv[(b * NN + r0 + row) * DE + d] : 0.f;
    sC[row * 168 + 32 + d] = (_Float16)vpp;
    sC[row * 168 + 96 + d] = (_Float16)vpv;
  }
  __syncthreads();
  int lane = tid & 63, wv = tid >> 6;
  int c = lane & 15, q = lane >> 4;
  half8 cf[5];
#pragma unroll
  for (int ks = 0; ks < 5; ks++)
    cf[ks] = *(const half8*)(&sC[c * 168 + ks * 32 + q * 8]);
#pragma unroll
  for (int nt2 = 0; nt2 < 2; nt2++) {
    int nt = wv * 2 + nt2;
    floatx4 a0 = {0.f, 0.f, 0.f, 0.f};
#pragma unroll
    for (int ks = 0; ks < 5; ks++) {
      half8 wf = *(const half8*)(&WT[OFF_FO1 + ((nt * 5 + ks) << 9) + (lane << 3)]);
      a0 = MFMA(wf, cf[ks], a0);
    }
    float4 bb = *(const float4*)(&fo1_b[nt * 16 + q * 4]);
    half4v h0;
    h0[0] = (_Float16)fmaxf(a0[0] + bb.x, 0.f);
    h0[1] = (_Float16)fmaxf(a0[1] + bb.y, 0.f);
    h0[2] = (_Float16)fmaxf(a0[2] + bb.z, 0.f);
    h0[3] = (_Float16)fmaxf(a0[3] + bb.w, 0.f);
    *(half4v*)(&sHa[c * PITCH + nt * 16 + q * 4]) = h0;
  }
  __syncthreads();
  half8 g1[4];
#pragma unroll
  for (int ks = 0; ks < 4; ks++)
    g1[ks] = *(const half8*)(&sHa[c * PITCH + ks * 32 + q * 8]);
#pragma unroll
  for (int nt2 = 0; nt2 < 2; nt2++) {
    int nt = wv * 2 + nt2;
    floatx4 a0 = {0.f, 0.f, 0.f, 0.f};
#pragma unroll
    for (int ks = 0; ks < 4; ks++) {
      half8 wf = *(const half8*)(&WT[OFF_FO2 + ((nt * 4 + ks) << 9) + (lane << 3)]);
      a0 = MFMA(wf, g1[ks], a0);
    }
    float4 bb = *(const float4*)(&fo2_b[nt * 16 + q * 4]);
    half4v h0;
    h0[0] = (_Float16)fmaxf(a0[0] + bb.x, 0.f);
    h0[1] = (_Float16)fmaxf(a0[1] + bb.y, 0.f);
    h0[2] = (_Float16)fmaxf(a0[2] + bb.z, 0.f);
    h0[3] = (_Float16)fmaxf(a0[3] + bb.w, 0.f);
    *(half4v*)(&sHb[c * PITCH + nt * 16 + q * 4]) = h0;
  }
  __syncthreads();
  half8 g2[4];
#pragma unroll
  for (int ks = 0; ks < 4; ks++)
    g2[ks] = *(const half8*)(&sHb[c * PITCH + ks * 32 + q * 8]);
  floatx4 e0 = {0.f, 0.f, 0.f, 0.f};
#pragma unroll
  for (int ks = 0; ks < 4; ks++) {
    half8 wf = *(const half8*)(&WT[OFF_FO3 + ((wv * 4 + ks) << 9) + (lane << 3)]);
    e0 = MFMA(g2[ks], wf, e0);
  }
  float bb3 = fo3_b[wv * 16 + c];
  float s = 0.f;
  if (q < 2) {
#pragma unroll
    for (int rg = 0; rg < 4; rg++) s += fmaxf(e0[rg] + bb3, 0.f);
  }
  s += __shfl_xor(s, 16);
  if (lane < 16) sPool[wv * 16 + c] = s;
  __syncthreads();
  if (tid < NCLS) {
    float o = ((blockIdx.x & 7) == 0) ? fc_b[tid] : 0.f;
#pragma unroll
    for (int d = 0; d < 64; d++) o += sPool[d] * fc_w[d * NCLS + tid];
    atomicAdd(&out[b * NCLS + tid], o);
  }
}

extern "C" void kernel_launch(void* const* d_in, const int* in_sizes, int n_in,
                              void* d_out, int out_size, void* d_ws, size_t ws_size,
                              hipStream_t stream) {
  const float* x = (const float*)d_in[0];
  const float* y = (const float*)d_in[1];
  const float* fr1_w = (const float*)d_in[2];  const float* fr1_b = (const float*)d_in[3];
  const float* fr2_w = (const float*)d_in[4];  const float* fr2_b = (const float*)d_in[5];
  const float* fr3_w = (const float*)d_in[6];  const float* fr3_b = (const float*)d_in[7];
  const float* fr1pv_w = (const float*)d_in[8];  const float* fr1pv_b = (const float*)d_in[9];
  const float* fr2pv_w = (const float*)d_in[10]; const float* fr2pv_b = (const float*)d_in[11];
  const float* fr3pv_w = (const float*)d_in[12]; const float* fr3pv_b = (const float*)d_in[13];
  const float* fo1_w = (const float*)d_in[14];  const float* fo1_b = (const float*)d_in[15];
  const float* fo2_w = (const float*)d_in[16];  const float* fo2_b = (const float*)d_in[17];
  const float* fo3_w = (const float*)d_in[18];  const float* fo3_b = (const float*)d_in[19];
  const float* fc_w = (const float*)d_in[20];   const float* fc_b = (const float*)d_in[21];

  char* ws = (char*)d_ws;
  _Float16* A1h   = (_Float16*)(ws);                 // [128][64][128] fp16 (bias folded)
  _Float16* B1h   = (_Float16*)(ws + (2u << 20));
  _Float16* A1pvh = (_Float16*)(ws + (4u << 20));    // (bias folded)
  _Float16* B1pvh = (_Float16*)(ws + (6u << 20));    // [128][14][128] fp16
  _Float16* WT    = (_Float16*)(ws + (7u << 20));    // frag-major fp16 weights (~200 KB)
  float* Epp      = (float*)(ws + (8u << 20));       // [128][64][64] f32
  float* Epv      = (float*)(ws + (10u << 20));      // [128][64][64] f32

  k0_prep<<<953, 256, 0, stream>>>(x, y, fr1_w, fr1_b, fr1pv_w, fr1pv_b,
                                   fr2_w, fr3_w, fr2pv_w, fr3pv_w,
                                   fo1_w, fo2_w, fo3_w,
                                   A1h, B1h, A1pvh, B1pvh, WT, (float*)d_out);
  edges<<<3072, 256, 0, stream>>>(A1h, B1h, A1pvh, B1pvh,
                                  fr2_b, fr3_b, fr2pv_b, fr3pv_b,
                                  WT, Epp, Epv);
  node_out<<<NB * 8, 256, 0, stream>>>(x, Epp, Epv, fo1_b, fo2_b, fo3_b,
                                       fc_w, fc_b, WT, (float*)d_out);
}